// Round 3
// baseline (120.694 us; speedup 1.0000x reference)
//
#include <hip/hip_runtime.h>

// Quanvolution + linear(784->10) + log_softmax, B=65536, fp32.
// R2: wave-private coalesced staging + register-double-buffer prefetch.
//  - block = 128 thr = 2 waves, 64 rows; wave h handles patch-rows 7h..7h+6
//  - staging: 64 rows x 224 B tile as 14 coalesced float4 loads/lane
//    (224-byte contiguous runs -> clean HBM granule consumption, per R0)
//  - prefetch: loads for patch-row ii+1 issued before compute of ii
//    (compiler emits counted vmcnt waits -> latency hidden, no barriers)
//  - W reads wave-uniform -> s_load broadcasts through K$
//  - single __syncthreads at the end for the 2-wave partial reduction

#define PADF 58   // LDS floats per row (56 data + 2 pad; even for float2 align)

__global__ __launch_bounds__(128, 2)
void quanv_fused3_kernel(const float* __restrict__ x,
                         const float* __restrict__ Wm,
                         const float* __restrict__ bias,
                         float* __restrict__ out) {
    __shared__ float sbuf[2][64 * PADF];   // 2 x 14848 B, one per wave
    __shared__ float part[64][10];         // 2560 B

    const int t  = threadIdx.x;
    const int l  = t & 63;
    const int h  = __builtin_amdgcn_readfirstlane(t >> 6);  // wave id 0/1
    const int R0 = blockIdx.x * 64;
    const float* xb = x + (size_t)R0 * 784;
    float* buf = sbuf[h];

    float acc[10];
#pragma unroll
    for (int k = 0; k < 10; ++k) acc[k] = 0.f;

    // quad-slot decomposition: slot j -> f = l + 64j, row = f/14, q = f%14
    int xoff[14];      // global float offset within block tile
    float* lp[14];     // LDS destination (addrspace(3), 32-bit regs)
#pragma unroll
    for (int j = 0; j < 14; ++j) {
        const int f   = l + 64 * j;
        const int row = f / 14;
        const int q   = f - 14 * row;
        xoff[j] = row * 784 + q * 4;
        lp[j]   = &buf[row * PADF + q * 4];
    }

    const int pr0 = h * 7;
    float4 A[14], B[14];

    // prologue: load patch-row pr0 into A
#pragma unroll
    for (int j = 0; j < 14; ++j)
        A[j] = *(const float4*)(xb + xoff[j] + pr0 * 56);

#pragma unroll
    for (int ii = 0; ii < 7; ++ii) {
        float4* CUR = (ii & 1) ? B : A;
        float4* NXT = (ii & 1) ? A : B;

        // prefetch next patch-row (stays in flight through compute)
        if (ii < 6) {
#pragma unroll
            for (int j = 0; j < 14; ++j)
                NXT[j] = *(const float4*)(xb + xoff[j] + (pr0 + ii + 1) * 56);
        }

        // stage current patch-row to this wave's LDS buffer
#pragma unroll
        for (int j = 0; j < 14; ++j)
            *(float4*)lp[j] = CUR[j];

        // wave-internal visibility: writes by other lanes -> my reads
        asm volatile("s_waitcnt lgkmcnt(0)" ::: "memory");
        __builtin_amdgcn_sched_barrier(0);

        const float* myrow = &buf[l * PADF];
        const float* wp = Wm + (pr0 + ii) * 56;   // 14 patches * 4 cols
#pragma unroll 2
        for (int pj = 0; pj < 14; ++pj) {
            const float2 a = *(const float2*)(myrow + 2 * pj);        // p0,p1
            const float2 b = *(const float2*)(myrow + 28 + 2 * pj);   // p2,p3
            const float c0 = __cosf(a.x), c1 = __cosf(a.y);
            const float c2 = __cosf(b.x), c3 = __cosf(b.y);
            const float f0 = c0 + a.x;
            const float f1 = c0 * c1 + a.y;
            const float f2 = c2 + b.x;
            const float f3 = c2 * c3 + b.y;
            const float* wq = wp + pj * 4;        // wave-uniform -> s_load
#pragma unroll
            for (int k = 0; k < 10; ++k) {
                const float4 w = *(const float4*)(wq + k * 784);
                acc[k] = fmaf(f0, w.x,
                         fmaf(f1, w.y,
                         fmaf(f2, w.z,
                         fmaf(f3, w.w, acc[k]))));
            }
        }

        // reads done before next iteration's ds_writes overwrite the buffer
        asm volatile("s_waitcnt lgkmcnt(0)" ::: "memory");
        __builtin_amdgcn_sched_barrier(0);
    }

    // ---- cross-wave reduction + bias + log_softmax + store ----
    if (h == 1) {
#pragma unroll
        for (int k = 0; k < 10; ++k) part[l][k] = acc[k];
    }
    __syncthreads();
    if (h == 0) {
        float m = -1e30f;
#pragma unroll
        for (int k = 0; k < 10; ++k) {
            acc[k] += part[l][k] + bias[k];
            m = fmaxf(m, acc[k]);
        }
        float s = 0.f;
#pragma unroll
        for (int k = 0; k < 10; ++k) s += __expf(acc[k] - m);
        const float ls = __logf(s) + m;
        float* o = out + (size_t)(R0 + l) * 10;
#pragma unroll
        for (int k = 0; k < 10; k += 2)
            *(float2*)(o + k) = make_float2(acc[k] - ls, acc[k + 1] - ls);
    }
}

extern "C" void kernel_launch(void* const* d_in, const int* in_sizes, int n_in,
                              void* d_out, int out_size, void* d_ws, size_t ws_size,
                              hipStream_t stream) {
    const float* x    = (const float*)d_in[0];   // [65536, 784]
    const float* Wm   = (const float*)d_in[1];   // [10, 784]
    const float* bias = (const float*)d_in[2];   // [10]
    float* out        = (float*)d_out;           // [65536, 10]

    quanv_fused3_kernel<<<dim3(1024), dim3(128), 0, stream>>>(x, Wm, bias, out);
}